// Round 14
// baseline (69.606 us; speedup 1.0000x reference)
//
#include <hip/hip_runtime.h>
#include <cmath>

#define NK        10000
#define GROUP     2000
#define SEQ_L     256
#define FEAT_DIM  20000
#define NBATCH    16
#define CONV_BLKS 640          // 8 Mtiles * 5 groups * 16 batches
#define NSLICE    40
#define SLICE_F   500
#define TOTAL_BLKS (CONV_BLKS + NSLICE)

typedef _Float16 half8 __attribute__((ext_vector_type(8)));
typedef float    f32x4 __attribute__((ext_vector_type(4)));

// ---------------------------------------------------------------------------
// Single compute dispatch. Roles by blockIdx:
//   bid <  640 : fused im2col + MFMA conv + max/PPV (R12-validated body).
//                Ends with fence + release-add on counters[0]. Never waits.
//   bid >= 640 : 40 BN blocks. tid0 spins (s_sleep) until counters[0]==640,
//                acquire fence, then BN+GEMV partial (R13 body, 500 feats),
//                last-arriver (counters[1]) does the fixed-order final reduce.
// Co-residency proof: 680 blocks, 32KB LDS, 4 waves, VGPR<=128 -> >=4
// blocks/CU capacity vs 680/256=2.7 needed; conv blocks are dependency-free.
// ---------------------------------------------------------------------------
__launch_bounds__(256)
__global__ void fused_all(const float* __restrict__ x_enc,  // (16,256,3)
                          const float* __restrict__ Wk,     // (10000,3,9)
                          const float* __restrict__ bias,   // (10000,)
                          const float* __restrict__ gamma,
                          const float* __restrict__ beta,
                          const float* __restrict__ linW,   // (20000,10)
                          const float* __restrict__ linB,   // (10,)
                          float* __restrict__ feat,         // ws (16,20000)
                          float* __restrict__ partial,      // ws (40,16,10)
                          unsigned* __restrict__ counters,  // ws, pre-zeroed
                          float* __restrict__ out)          // (16,10)
{
    __shared__ __align__(16) char smem[32768 + 16];
    const int bid = blockIdx.x;
    const int tid = threadIdx.x;

    if (bid < CONV_BLKS) {
        // ================= conv role =================
        _Float16* Bh = (_Float16*)smem;              // [q*256+t][j] 16 KB
        _Float16* Bl = (_Float16*)(smem + 16384);    // 16 KB

        const int mt = bid / 80;           // 0..7 (256 rows each)
        const int rr = bid - mt * 80;
        const int gi = rr >> 4;            // dilation group 0..4
        const int b  = rr & 15;
        const int d  = 1 << gi;
        const int l  = tid & 63;
        const int wv = tid >> 6;           // wave -> 64-row slice
        const int kb = l >> 4;             // k-block 0..3
        const int lr = l & 15;

        // ---- A fragments (weights + bias folded at k=27) -> registers ----
        half8 ahi[4], alo[4];
#pragma unroll
        for (int tt = 0; tt < 4; ++tt) {
            const int nl = mt * 256 + wv * 64 + tt * 16 + lr;
            const int n  = gi * GROUP + (nl < GROUP ? nl : GROUP - 1);
#pragma unroll
            for (int j = 0; j < 8; ++j) {
                const int k = kb * 8 + j;
                float w;
                if (k < 27)       w = Wk[n * 27 + k];
                else if (k == 27) w = bias[n];
                else              w = 0.f;
                const _Float16 h = (_Float16)w;
                ahi[tt][j] = h;
                alo[tt][j] = (_Float16)(w - (float)h);
            }
        }

        // ---- build B hi/lo in LDS direct from global x (thread = col t) ----
#pragma unroll
        for (int q = 0; q < 4; ++q) {
            half8 hv, lv;
#pragma unroll
            for (int kk = 0; kk < 8; ++kk) {
                const int k2 = q * 8 + kk;
                float v = 0.f;
                if (k2 < 27) {
                    const int c  = k2 / 9;
                    const int k9 = k2 - c * 9;
                    const int t2 = tid + (k9 - 4) * d;
                    if (t2 >= 0 && t2 < SEQ_L)
                        v = x_enc[(b * SEQ_L + t2) * 3 + c];
                } else if (k2 == 27) {
                    v = 1.0f;              // bias row
                }
                const _Float16 h = (_Float16)v;
                hv[kk] = h;
                lv[kk] = (_Float16)(v - (float)h);
            }
            *(half8*)&Bh[(q * 256 + tid) * 8] = hv;
            *(half8*)&Bl[(q * 256 + tid) * 8] = lv;
        }
        __syncthreads();

        // ---- MFMA main loop: 16 N-chunks of 16 cols ----
        float mx[4][4];
        int   cnt[4][4];
#pragma unroll
        for (int tt = 0; tt < 4; ++tt)
#pragma unroll
            for (int r = 0; r < 4; ++r) { mx[tt][r] = -INFINITY; cnt[tt][r] = 0; }

#pragma unroll
        for (int ch = 0; ch < 16; ++ch) {
            const int t = ch * 16 + lr;
            const half8 bh = *(const half8*)&Bh[(kb * 256 + t) * 8];
            const half8 bl = *(const half8*)&Bl[(kb * 256 + t) * 8];
#pragma unroll
            for (int tt = 0; tt < 4; ++tt) {
                f32x4 acc = {0.f, 0.f, 0.f, 0.f};
                acc = __builtin_amdgcn_mfma_f32_16x16x32_f16(ahi[tt], bh, acc, 0, 0, 0);
                acc = __builtin_amdgcn_mfma_f32_16x16x32_f16(alo[tt], bh, acc, 0, 0, 0);
                acc = __builtin_amdgcn_mfma_f32_16x16x32_f16(ahi[tt], bl, acc, 0, 0, 0);
#pragma unroll
                for (int r = 0; r < 4; ++r) {
                    const float y = acc[r];            // bias already included
                    mx[tt][r]   = fmaxf(mx[tt][r], y);
                    cnt[tt][r] += (y > 0.f) ? 1 : 0;
                }
            }
        }

        // ---- reduce over 16 columns ----
#pragma unroll
        for (int tt = 0; tt < 4; ++tt)
#pragma unroll
            for (int r = 0; r < 4; ++r) {
#pragma unroll
                for (int m = 1; m < 16; m <<= 1) {
                    mx[tt][r]   = fmaxf(mx[tt][r], __shfl_xor(mx[tt][r], m));
                    cnt[tt][r] += __shfl_xor(cnt[tt][r], m);
                }
            }

        if (lr == 0) {
            float* fb = feat + b * FEAT_DIM + gi * 4000;
#pragma unroll
            for (int tt = 0; tt < 4; ++tt)
#pragma unroll
                for (int r = 0; r < 4; ++r) {
                    const int nl = mt * 256 + wv * 64 + tt * 16 + kb * 4 + r;
                    if (nl < GROUP) {
                        fb[nl]        = mx[tt][r];
                        fb[2000 + nl] = (float)cnt[tt][r] * (1.0f / 256.0f);
                    }
                }
        }

        // ---- arrival: all waves' stores drained at barrier, then release ----
        __syncthreads();
        if (tid == 0) {
            __threadfence();               // write back dirty L2 lines
            __hip_atomic_fetch_add(&counters[0], 1u, __ATOMIC_RELEASE,
                                   __HIP_MEMORY_SCOPE_AGENT);
        }
    } else {
        // ================= BN + GEMV role (40 blocks) =================
        float* gs  = (float*)smem;                   // 500
        float* hs  = gs + SLICE_F;                   // 500
        float* lw  = hs + SLICE_F;                   // 5000 (ends at 24000 B)
        int*   flg = (int*)(smem + 24064);

        const int sl = bid - CONV_BLKS;    // 0..39
        const int f0 = sl * SLICE_F;

        // ---- wait for all conv blocks (only 40 spinners, s_sleep) ----
        if (tid == 0) {
            while (__hip_atomic_load(&counters[0], __ATOMIC_ACQUIRE,
                                     __HIP_MEMORY_SCOPE_AGENT) < CONV_BLKS)
                __builtin_amdgcn_s_sleep(32);
            __threadfence();               // acquire: invalidate stale L1/L2
        }
        __syncthreads();

        for (int i = tid; i < SLICE_F * 10; i += 256) lw[i] = linW[f0 * 10 + i];

        for (int i = tid; i < SLICE_F; i += 256) {
            const int f = f0 + i;
            float s = 0.f, ss = 0.f;
#pragma unroll
            for (int b = 0; b < NBATCH; ++b) {
                const float v = feat[b * FEAT_DIM + f];
                s += v; ss += v * v;
            }
            const float mu  = s * (1.f / NBATCH);
            const float var = ss * (1.f / NBATCH) - mu * mu;
            const float gg  = gamma[f] * rsqrtf(var + 1e-5f);
            gs[i] = gg;
            hs[i] = beta[f] - mu * gg;
        }
        __syncthreads();

        const int bb = tid >> 4;           // batch 0..15
        const int ft = tid & 15;
        float acc[10];
#pragma unroll
        for (int c = 0; c < 10; ++c) acc[c] = 0.f;

        for (int i = ft; i < SLICE_F; i += 16) {
            const float tv = fmaf(feat[bb * FEAT_DIM + f0 + i], gs[i], hs[i]);
#pragma unroll
            for (int c = 0; c < 10; ++c) acc[c] = fmaf(tv, lw[i * 10 + c], acc[c]);
        }
#pragma unroll
        for (int c = 0; c < 10; ++c)
#pragma unroll
            for (int m = 1; m < 16; m <<= 1) acc[c] += __shfl_xor(acc[c], m);

        if (ft == 0) {
#pragma unroll
            for (int c = 0; c < 10; ++c)
                partial[(sl * NBATCH + bb) * 10 + c] = acc[c];
        }

        // ---- last-arriver final reduce (R13-validated, no spinning) ----
        __syncthreads();                   // drains partial stores
        if (tid == 0) {
            __threadfence();
            const unsigned old =
                __hip_atomic_fetch_add(&counters[1], 1u, __ATOMIC_ACQ_REL,
                                       __HIP_MEMORY_SCOPE_AGENT);
            *flg = (old == NSLICE - 1);
        }
        __syncthreads();

        if (*flg) {
            __threadfence();
            if (tid < 160) {               // o = b*10 + c
                float s = linB[tid % 10];
#pragma unroll
                for (int q = 0; q < NSLICE; ++q)
                    s += __hip_atomic_load(&partial[q * 160 + tid],
                                           __ATOMIC_RELAXED,
                                           __HIP_MEMORY_SCOPE_AGENT);
                out[tid] = s;
            }
        }
    }
}

// ---------------------------------------------------------------------------
extern "C" void kernel_launch(void* const* d_in, const int* in_sizes, int n_in,
                              void* d_out, int out_size, void* d_ws, size_t ws_size,
                              hipStream_t stream) {
    const float* x     = (const float*)d_in[0];
    const float* Wk    = (const float*)d_in[1];
    const float* bias  = (const float*)d_in[2];
    const float* gamma = (const float*)d_in[3];
    const float* beta  = (const float*)d_in[4];
    const float* linW  = (const float*)d_in[5];
    const float* linB  = (const float*)d_in[6];
    float* out = (float*)d_out;

    float*    feat     = (float*)d_ws;                   // 320000 f
    float*    partial  = feat + NBATCH * FEAT_DIM;       // 6400 f
    unsigned* counters = (unsigned*)(partial + NSLICE * 160);

    hipMemsetAsync(counters, 0, 2 * sizeof(unsigned), stream);
    fused_all<<<dim3(TOTAL_BLKS), 256, 0, stream>>>(x, Wk, bias, gamma, beta,
                                                    linW, linB, feat, partial,
                                                    counters, out);
}

// Round 15
// 50.215 us; speedup vs baseline: 1.3862x; 1.3862x over previous
//
#include <hip/hip_runtime.h>
#include <cmath>

#define NK        10000
#define GROUP     2000
#define SEQ_L     256
#define FEAT_DIM  20000
#define NBATCH    16
#define CONV_BLKS 640          // 8 Mtiles * 5 groups * 16 batches
#define NSLICE    40
#define SLICE_F   500
#define TOTAL_BLKS (CONV_BLKS + NSLICE)

typedef _Float16 half8 __attribute__((ext_vector_type(8)));
typedef float    f32x4 __attribute__((ext_vector_type(4)));

// ---------------------------------------------------------------------------
// Single compute dispatch, NO __threadfence anywhere.
//   bid < 640 : fused im2col + MFMA conv + max/PPV (R12-validated math).
//               feat written via agent-scope atomic stores (write-through to
//               the coherence point); one release fetch_add on counters[0].
//   bid >= 640: 40 BN blocks; tid0 sleeps until counters[0]==640 (acquire),
//               feat read via agent-scope atomic loads (bypass stale L2) --
//               the same access mode R12/R13 validated for `partial`.
//               Last arriver on counters[1] does the fixed-order final reduce.
// Co-residency: 680 blocks x 32.8KB LDS -> 4 blocks/CU -> capacity 1024.
// ---------------------------------------------------------------------------
__launch_bounds__(256)
__global__ void fused_all(const float* __restrict__ x_enc,  // (16,256,3)
                          const float* __restrict__ Wk,     // (10000,3,9)
                          const float* __restrict__ bias,   // (10000,)
                          const float* __restrict__ gamma,
                          const float* __restrict__ beta,
                          const float* __restrict__ linW,   // (20000,10)
                          const float* __restrict__ linB,   // (10,)
                          float* __restrict__ feat,         // ws (16,20000)
                          float* __restrict__ partial,      // ws (40,16,10)
                          unsigned* __restrict__ counters,  // ws, pre-zeroed
                          float* __restrict__ out)          // (16,10)
{
    __shared__ __align__(16) char smem[32768 + 16];
    const int bid = blockIdx.x;
    const int tid = threadIdx.x;

    if (bid < CONV_BLKS) {
        // ================= conv role =================
        _Float16* Bh = (_Float16*)smem;              // [q*256+t][j] 16 KB
        _Float16* Bl = (_Float16*)(smem + 16384);    // 16 KB

        const int mt = bid / 80;           // 0..7 (256 rows each)
        const int rr = bid - mt * 80;
        const int gi = rr >> 4;            // dilation group 0..4
        const int b  = rr & 15;
        const int d  = 1 << gi;
        const int l  = tid & 63;
        const int wv = tid >> 6;           // wave -> 64-row slice
        const int kb = l >> 4;             // k-block 0..3
        const int lr = l & 15;

        // ---- A fragments (weights + bias folded at k=27) -> registers ----
        half8 ahi[4], alo[4];
#pragma unroll
        for (int tt = 0; tt < 4; ++tt) {
            const int nl = mt * 256 + wv * 64 + tt * 16 + lr;
            const int n  = gi * GROUP + (nl < GROUP ? nl : GROUP - 1);
#pragma unroll
            for (int j = 0; j < 8; ++j) {
                const int k = kb * 8 + j;
                float w;
                if (k < 27)       w = Wk[n * 27 + k];
                else if (k == 27) w = bias[n];
                else              w = 0.f;
                const _Float16 h = (_Float16)w;
                ahi[tt][j] = h;
                alo[tt][j] = (_Float16)(w - (float)h);
            }
        }

        // ---- build B hi/lo in LDS direct from global x (thread = col t) ----
#pragma unroll
        for (int q = 0; q < 4; ++q) {
            half8 hv, lv;
#pragma unroll
            for (int kk = 0; kk < 8; ++kk) {
                const int k2 = q * 8 + kk;
                float v = 0.f;
                if (k2 < 27) {
                    const int c  = k2 / 9;
                    const int k9 = k2 - c * 9;
                    const int t2 = tid + (k9 - 4) * d;
                    if (t2 >= 0 && t2 < SEQ_L)
                        v = x_enc[(b * SEQ_L + t2) * 3 + c];
                } else if (k2 == 27) {
                    v = 1.0f;              // bias row
                }
                const _Float16 h = (_Float16)v;
                hv[kk] = h;
                lv[kk] = (_Float16)(v - (float)h);
            }
            *(half8*)&Bh[(q * 256 + tid) * 8] = hv;
            *(half8*)&Bl[(q * 256 + tid) * 8] = lv;
        }
        __syncthreads();

        // ---- MFMA main loop: 16 N-chunks of 16 cols ----
        float mx[4][4];
        int   cnt[4][4];
#pragma unroll
        for (int tt = 0; tt < 4; ++tt)
#pragma unroll
            for (int r = 0; r < 4; ++r) { mx[tt][r] = -INFINITY; cnt[tt][r] = 0; }

#pragma unroll
        for (int ch = 0; ch < 16; ++ch) {
            const int t = ch * 16 + lr;
            const half8 bh = *(const half8*)&Bh[(kb * 256 + t) * 8];
            const half8 bl = *(const half8*)&Bl[(kb * 256 + t) * 8];
#pragma unroll
            for (int tt = 0; tt < 4; ++tt) {
                f32x4 acc = {0.f, 0.f, 0.f, 0.f};
                acc = __builtin_amdgcn_mfma_f32_16x16x32_f16(ahi[tt], bh, acc, 0, 0, 0);
                acc = __builtin_amdgcn_mfma_f32_16x16x32_f16(alo[tt], bh, acc, 0, 0, 0);
                acc = __builtin_amdgcn_mfma_f32_16x16x32_f16(ahi[tt], bl, acc, 0, 0, 0);
#pragma unroll
                for (int r = 0; r < 4; ++r) {
                    const float y = acc[r];            // bias already included
                    mx[tt][r]   = fmaxf(mx[tt][r], y);
                    cnt[tt][r] += (y > 0.f) ? 1 : 0;
                }
            }
        }

        // ---- reduce over 16 columns ----
#pragma unroll
        for (int tt = 0; tt < 4; ++tt)
#pragma unroll
            for (int r = 0; r < 4; ++r) {
#pragma unroll
                for (int m = 1; m < 16; m <<= 1) {
                    mx[tt][r]   = fmaxf(mx[tt][r], __shfl_xor(mx[tt][r], m));
                    cnt[tt][r] += __shfl_xor(cnt[tt][r], m);
                }
            }

        // ---- feat stores: agent-scope atomic (write-through, no fence) ----
        if (lr == 0) {
            float* fb = feat + b * FEAT_DIM + gi * 4000;
#pragma unroll
            for (int tt = 0; tt < 4; ++tt)
#pragma unroll
                for (int r = 0; r < 4; ++r) {
                    const int nl = mt * 256 + wv * 64 + tt * 16 + kb * 4 + r;
                    if (nl < GROUP) {
                        __hip_atomic_store(&fb[nl], mx[tt][r],
                                           __ATOMIC_RELAXED,
                                           __HIP_MEMORY_SCOPE_AGENT);
                        __hip_atomic_store(&fb[2000 + nl],
                                           (float)cnt[tt][r] * (1.0f / 256.0f),
                                           __ATOMIC_RELAXED,
                                           __HIP_MEMORY_SCOPE_AGENT);
                    }
                }
        }

        __syncthreads();                   // drains vmcnt for all waves
        if (tid == 0)
            __hip_atomic_fetch_add(&counters[0], 1u, __ATOMIC_RELEASE,
                                   __HIP_MEMORY_SCOPE_AGENT);
    } else {
        // ================= BN + GEMV role (40 blocks) =================
        float* gs  = (float*)smem;                   // 500
        float* hs  = gs + SLICE_F;                   // 500
        float* lw  = hs + SLICE_F;                   // 5000 (ends at 24000 B)
        int*   flg = (int*)(smem + 24064);

        const int sl = bid - CONV_BLKS;    // 0..39
        const int f0 = sl * SLICE_F;

        // stage linW while waiting costs nothing to order before the wait
        for (int i = tid; i < SLICE_F * 10; i += 256) lw[i] = linW[f0 * 10 + i];

        if (tid == 0) {
            while (__hip_atomic_load(&counters[0], __ATOMIC_ACQUIRE,
                                     __HIP_MEMORY_SCOPE_AGENT) < CONV_BLKS)
                __builtin_amdgcn_s_sleep(16);
        }
        __syncthreads();

        // ---- BN stats: feat via agent atomic loads (bypass stale L2) ----
        for (int i = tid; i < SLICE_F; i += 256) {
            const int f = f0 + i;
            float s = 0.f, ss = 0.f;
#pragma unroll
            for (int b = 0; b < NBATCH; ++b) {
                const float v = __hip_atomic_load(&feat[b * FEAT_DIM + f],
                                                  __ATOMIC_RELAXED,
                                                  __HIP_MEMORY_SCOPE_AGENT);
                s += v; ss += v * v;
            }
            const float mu  = s * (1.f / NBATCH);
            const float var = ss * (1.f / NBATCH) - mu * mu;
            const float gg  = gamma[f] * rsqrtf(var + 1e-5f);
            gs[i] = gg;
            hs[i] = beta[f] - mu * gg;
        }
        __syncthreads();

        const int bb = tid >> 4;           // batch 0..15
        const int ft = tid & 15;
        float acc[10];
#pragma unroll
        for (int c = 0; c < 10; ++c) acc[c] = 0.f;

        for (int i = ft; i < SLICE_F; i += 16) {
            const float fv = __hip_atomic_load(&feat[bb * FEAT_DIM + f0 + i],
                                               __ATOMIC_RELAXED,
                                               __HIP_MEMORY_SCOPE_AGENT);
            const float tv = fmaf(fv, gs[i], hs[i]);
#pragma unroll
            for (int c = 0; c < 10; ++c) acc[c] = fmaf(tv, lw[i * 10 + c], acc[c]);
        }
#pragma unroll
        for (int c = 0; c < 10; ++c)
#pragma unroll
            for (int m = 1; m < 16; m <<= 1) acc[c] += __shfl_xor(acc[c], m);

        if (ft == 0) {
#pragma unroll
            for (int c = 0; c < 10; ++c)
                __hip_atomic_store(&partial[(sl * NBATCH + bb) * 10 + c], acc[c],
                                   __ATOMIC_RELAXED, __HIP_MEMORY_SCOPE_AGENT);
        }

        // ---- last-arriver final reduce (R13-validated) ----
        __syncthreads();                   // drains partial stores
        if (tid == 0) {
            const unsigned old =
                __hip_atomic_fetch_add(&counters[1], 1u, __ATOMIC_ACQ_REL,
                                       __HIP_MEMORY_SCOPE_AGENT);
            *flg = (old == NSLICE - 1);
        }
        __syncthreads();

        if (*flg) {
            if (tid < 160) {               // o = b*10 + c
                float s = linB[tid % 10];
#pragma unroll
                for (int q = 0; q < NSLICE; ++q)
                    s += __hip_atomic_load(&partial[q * 160 + tid],
                                           __ATOMIC_RELAXED,
                                           __HIP_MEMORY_SCOPE_AGENT);
                out[tid] = s;
            }
        }
    }
}

// ---------------------------------------------------------------------------
extern "C" void kernel_launch(void* const* d_in, const int* in_sizes, int n_in,
                              void* d_out, int out_size, void* d_ws, size_t ws_size,
                              hipStream_t stream) {
    const float* x     = (const float*)d_in[0];
    const float* Wk    = (const float*)d_in[1];
    const float* bias  = (const float*)d_in[2];
    const float* gamma = (const float*)d_in[3];
    const float* beta  = (const float*)d_in[4];
    const float* linW  = (const float*)d_in[5];
    const float* linB  = (const float*)d_in[6];
    float* out = (float*)d_out;

    float*    feat     = (float*)d_ws;                   // 320000 f
    float*    partial  = feat + NBATCH * FEAT_DIM;       // 6400 f
    unsigned* counters = (unsigned*)(partial + NSLICE * 160);

    hipMemsetAsync(counters, 0, 2 * sizeof(unsigned), stream);
    fused_all<<<dim3(TOTAL_BLKS), 256, 0, stream>>>(x, Wk, bias, gamma, beta,
                                                    linW, linB, feat, partial,
                                                    counters, out);
}